// Round 8
// baseline (162.074 us; speedup 1.0000x reference)
//
#include <hip/hip_runtime.h>
#include <hip/hip_bf16.h>
#include <math.h>

#define BB 4
#define NN 4096
#define CCH 256
#define HEADS 8
#define HD 32
#define NKV 1024
#define EPS_LN 1e-5f

typedef short short8 __attribute__((ext_vector_type(8)));
typedef float floatx4 __attribute__((ext_vector_type(4)));

// scale = HD^-0.5 folded with log2(e): softmax runs in exp2 domain
#define QSCALE (0.17677669529663687f * 1.4426950408889634f)

__device__ __forceinline__ unsigned pk_bf16(float a, float b) {
  __hip_bfloat162 h = __float22bfloat162_rn(make_float2(a, b));
  unsigned u; __builtin_memcpy(&u, &h, 4); return u;
}

__device__ __forceinline__ short8 cvt8(float4 a, float4 b) {
  union { short8 s; unsigned u[4]; } r;
  r.u[0] = pk_bf16(a.x, a.y); r.u[1] = pk_bf16(a.z, a.w);
  r.u[2] = pk_bf16(b.x, b.y); r.u[3] = pk_bf16(b.z, b.w);
  return r.s;
}

// async global->LDS, 16B per lane; LDS dest is wave-uniform base + lane*16
__device__ __forceinline__ void gl_lds16(const unsigned short* g, unsigned short* l) {
  __builtin_amdgcn_global_load_lds(
      (const __attribute__((address_space(1))) void*)g,
      (__attribute__((address_space(3))) void*)l, 16, 0, 0);
}

// ---------------------------------------------------------------------------
// Cast weights fp32 -> bf16, FRAGMENT-MAJOR swizzle:
// unit(row,col) = ((row>>4)*(Kd/32) + (col>>5))*64 + ((col>>3)&3)*16 + (row&15)
// -> a wave's wf load is one contiguous 1KB segment. QSCALE folded into q_w.
// ---------------------------------------------------------------------------
__global__ __launch_bounds__(256) void cast_weights(
    const float* __restrict__ q_w, const float* __restrict__ kv_w,
    const float* __restrict__ sr_w, const float* __restrict__ proj_w,
    unsigned short* __restrict__ q_wbf, unsigned short* __restrict__ kv_wbf,
    unsigned short* __restrict__ sr_wbf, unsigned short* __restrict__ proj_wbf) {
  const int e = (blockIdx.x * 256 + threadIdx.x) * 8;
  const float* src; unsigned short* dst; int off; int shift, kdu; float sc = 1.f;
  if (e < 65536)       { src = q_w;    dst = q_wbf;    off = e;          shift = 8;  kdu = 8;  sc = QSCALE; }
  else if (e < 196608) { src = kv_w;   dst = kv_wbf;   off = e - 65536;  shift = 8;  kdu = 8; }
  else if (e < 458752) { src = sr_w;   dst = sr_wbf;   off = e - 196608; shift = 10; kdu = 32; }
  else                 { src = proj_w; dst = proj_wbf; off = e - 458752; shift = 8;  kdu = 8; }
  const int row = off >> shift;
  const int col = off & ((1 << shift) - 1);
  const int unit = ((row >> 4) * kdu + (col >> 5)) * 64 + ((col >> 3) & 3) * 16 + (row & 15);
  float4 a = *(const float4*)&src[off];
  float4 b = *(const float4*)&src[off + 4];
  a.x *= sc; a.y *= sc; a.z *= sc; a.w *= sc;
  b.x *= sc; b.y *= sc; b.z *= sc; b.w *= sc;
  *(short8*)&dst[unit * 8] = cvt8(a, b);
}

// X-tile LDS layout (16 tokens x 32 16B-units, 33-unit skew)
#define XU16(t, u) (((t) * 33 + (u)) * 8)

// ---------------------------------------------------------------------------
// Fused Q-projection + (SR-conv + LN + KV-projection).
// Grid 1280 x 256 thr: bx < 1024 -> Q tile (16 tok x 256 ch);
// bx >= 1024    -> conv tile: 16 kv tok, conv full-K per wave (64 ch/wave),
//                  in-LDS LN, then KV GEMM (128 ch/wave) from the LDS tile.
// ---------------------------------------------------------------------------
__global__ __launch_bounds__(256) void qconv_gemm(const float* __restrict__ x,
    const unsigned short* __restrict__ q_wbf, const float* __restrict__ q_b,
    const unsigned short* __restrict__ sr_wbf, const float* __restrict__ sr_b,
    const float* __restrict__ ln_g, const float* __restrict__ ln_b,
    const unsigned short* __restrict__ kv_wbf, const float* __restrict__ kv_b,
    unsigned short* __restrict__ qbf,
    unsigned short* __restrict__ kbf, unsigned short* __restrict__ vtbf) {
  __shared__ unsigned short sm[20736];   // conv: patch 2064u + xln 528u = 41.5KB
  const int tid = threadIdx.x, w = tid >> 6, lnn = tid & 63;
  const int l15 = lnn & 15, qd = lnn >> 4;

  if (blockIdx.x < 1024) {
    // ---------------- Q projection tile ----------------
    const long tok0 = (long)blockIdx.x * 16;
    const float* Xg = x + tok0 * 256;
#pragma unroll
    for (int j = 0; j < 2; ++j) {
      const int idx = j * 256 + tid;
      const int tok = idx >> 5, u = idx & 31;
      float4 a = *(const float4*)(Xg + (size_t)tok * 256 + u * 8);
      float4 b = *(const float4*)(Xg + (size_t)tok * 256 + u * 8 + 4);
      *(short8*)(sm + XU16(tok, u)) = cvt8(a, b);
    }
    __syncthreads();
    floatx4 acc[4];
#pragma unroll
    for (int ct = 0; ct < 4; ++ct) for (int r = 0; r < 4; ++r) acc[ct][r] = 0.f;
    const unsigned short* wb = q_wbf + (size_t)(w * 4) * 4096 + lnn * 8;
#pragma unroll
    for (int kc = 0; kc < 8; ++kc) {
      short8 xf = *(const short8*)(sm + XU16(l15, kc * 4 + qd));
#pragma unroll
      for (int ct = 0; ct < 4; ++ct) {
        short8 wf = *(const short8*)(wb + (ct * 8 + kc) * 512);
        acc[ct] = __builtin_amdgcn_mfma_f32_16x16x32_bf16(wf, xf, acc[ct], 0, 0, 0);
      }
    }
    const int tok = (int)tok0 + l15;
    const int b = tok >> 12, trow = tok & 4095;
    const int chb = w * 64;
#pragma unroll
    for (int ct = 0; ct < 4; ++ct) {
      const int ch = chb + ct * 16 + qd * 4;
      float4 bb = *(const float4*)&q_b[ch];
      uint2 u;
      u.x = pk_bf16(acc[ct][0] + bb.x * QSCALE, acc[ct][1] + bb.y * QSCALE);
      u.y = pk_bf16(acc[ct][2] + bb.z * QSCALE, acc[ct][3] + bb.w * QSCALE);
      const int h = ch >> 5, d0 = ch & 31;
      *(uint2*)&qbf[((size_t)(b * HEADS + h) * NN + trow) * HD + d0] = u;
    }
    return;
  }

  // ---------------- conv + LN + KV tile ----------------
  unsigned short* xs = sm + 16512;       // xln tile 16x33 units (8448 B)
  const int gt0 = (blockIdx.x - 1024) * 16;
  const int b = gt0 >> 10, tl = gt0 & 1023;
  // stage 16 tokens x 1024 patch feats (f = c*4 + di*2 + dj), bf16, 129-skew
#pragma unroll
  for (int j = 0; j < 8; ++j) {
    const int g = j * 256 + tid;
    const int tk = g >> 7, u = g & 127;
    const int c0 = u * 2;
    const int tt = tl + tk;
    const int ti = tt >> 5, tj = tt & 31;
    float4 va, vb;
    float* pa = (float*)&va; float* pb = (float*)&vb;
#pragma unroll
    for (int q = 0; q < 4; ++q) {
      const int row = (2 * ti + (q >> 1)) * 64 + 2 * tj + (q & 1);
      const float* s = &x[((size_t)b * NN + row) * CCH + c0];
      pa[q] = s[0]; pb[q] = s[1];
    }
    *(short8*)(sm + (tk * 129 + u) * 8) = cvt8(va, vb);
  }
  __syncthreads();
  floatx4 acc[4];
#pragma unroll
  for (int ct = 0; ct < 4; ++ct) for (int r = 0; r < 4; ++r) acc[ct][r] = 0.f;
  // full K=1024 per wave; swizzled sr_w: wf(ct,kc) at ((w*4+ct)*32 + kc)*512
  const unsigned short* wbc = sr_wbf + lnn * 8;
#pragma unroll
  for (int kc = 0; kc < 32; ++kc) {
    short8 xf = *(const short8*)(sm + (l15 * 129 + kc * 4 + qd) * 8);
#pragma unroll
    for (int ct = 0; ct < 4; ++ct) {
      short8 wf = *(const short8*)(wbc + ((w * 4 + ct) * 32 + kc) * 512);
      acc[ct] = __builtin_amdgcn_mfma_f32_16x16x32_bf16(wf, xf, acc[ct], 0, 0, 0);
    }
  }
  __syncthreads();   // patch consumed
  float* ft = (float*)sm;   // [16][260] fp32 tile (reuses patch area)
#pragma unroll
  for (int ct = 0; ct < 4; ++ct) {
    float4 o;
    o.x = acc[ct][0]; o.y = acc[ct][1]; o.z = acc[ct][2]; o.w = acc[ct][3];
    *(float4*)&ft[l15 * 260 + w * 64 + ct * 16 + qd * 4] = o;
  }
  __syncthreads();
  // LN: thread = (token tk = tid>>4, 16-ch slice l16 = tid&15); 16-lane reduce
  {
    const int tk = tid >> 4, l16 = tid & 15;
    float v[16];
    float4* vv = (float4*)v;
#pragma unroll
    for (int m = 0; m < 4; ++m) {
      float4 t = *(float4*)&ft[tk * 260 + l16 * 16 + m * 4];
      float4 sb = *(const float4*)&sr_b[l16 * 16 + m * 4];
      t.x += sb.x; t.y += sb.y; t.z += sb.z; t.w += sb.w;
      vv[m] = t;
    }
    float s1 = 0.f, s2 = 0.f;
#pragma unroll
    for (int i = 0; i < 16; ++i) { s1 += v[i]; s2 += v[i] * v[i]; }
#pragma unroll
    for (int off = 1; off < 16; off <<= 1) {
      s1 += __shfl_xor(s1, off);
      s2 += __shfl_xor(s2, off);
    }
    const float mu = s1 * (1.f / 256.f);
    const float rstd = rsqrtf(s2 * (1.f / 256.f) - mu * mu + EPS_LN);
#pragma unroll
    for (int m = 0; m < 2; ++m) {
      float4 ga = *(const float4*)&ln_g[l16 * 16 + m * 8];
      float4 gb = *(const float4*)&ln_g[l16 * 16 + m * 8 + 4];
      float4 ba = *(const float4*)&ln_b[l16 * 16 + m * 8];
      float4 bb = *(const float4*)&ln_b[l16 * 16 + m * 8 + 4];
      float4 oa, ob;
      oa.x = (vv[m * 2].x - mu) * rstd * ga.x + ba.x;
      oa.y = (vv[m * 2].y - mu) * rstd * ga.y + ba.y;
      oa.z = (vv[m * 2].z - mu) * rstd * ga.z + ba.z;
      oa.w = (vv[m * 2].w - mu) * rstd * ga.w + ba.w;
      ob.x = (vv[m * 2 + 1].x - mu) * rstd * gb.x + bb.x;
      ob.y = (vv[m * 2 + 1].y - mu) * rstd * gb.y + bb.y;
      ob.z = (vv[m * 2 + 1].z - mu) * rstd * gb.z + bb.z;
      ob.w = (vv[m * 2 + 1].w - mu) * rstd * gb.w + bb.w;
      *(short8*)(xs + XU16(tk, l16 * 2 + m)) = cvt8(oa, ob);
    }
  }
  __syncthreads();
  // KV GEMM: wave w -> 128 out-chs [w*128, w*128+128); w<2 K-chs, w>=2 V-chs
  const bool isV = (w >= 2);
  const int chb = w * 128;
  floatx4 kacc[8];
#pragma unroll
  for (int ct = 0; ct < 8; ++ct) for (int r = 0; r < 4; ++r) kacc[ct][r] = 0.f;
  const unsigned short* wb = kv_wbf + (size_t)(chb >> 4) * 4096 + lnn * 8;
  if (!isV) {
#pragma unroll
    for (int kc = 0; kc < 8; ++kc) {
      short8 xf = *(const short8*)(xs + XU16(l15, kc * 4 + qd));
#pragma unroll
      for (int ct = 0; ct < 8; ++ct) {
        short8 wf = *(const short8*)(wb + (ct * 8 + kc) * 512);
        kacc[ct] = __builtin_amdgcn_mfma_f32_16x16x32_bf16(wf, xf, kacc[ct], 0, 0, 0);
      }
    }
    const int tok = tl + l15;
#pragma unroll
    for (int ct = 0; ct < 8; ++ct) {
      const int ch = chb + ct * 16 + qd * 4;
      float4 bb = *(const float4*)&kv_b[ch];
      uint2 u;
      u.x = pk_bf16(kacc[ct][0] + bb.x, kacc[ct][1] + bb.y);
      u.y = pk_bf16(kacc[ct][2] + bb.z, kacc[ct][3] + bb.w);
      const int h = ch >> 5, d0 = ch & 31;
      *(uint2*)&kbf[((size_t)(b * HEADS + h) * NKV + tok) * HD + d0] = u;
    }
  } else {
#pragma unroll
    for (int kc = 0; kc < 8; ++kc) {
      short8 xf = *(const short8*)(xs + XU16(l15, kc * 4 + qd));
#pragma unroll
      for (int ct = 0; ct < 8; ++ct) {
        short8 wf = *(const short8*)(wb + (ct * 8 + kc) * 512);
        kacc[ct] = __builtin_amdgcn_mfma_f32_16x16x32_bf16(xf, wf, kacc[ct], 0, 0, 0);
      }
    }
#pragma unroll
    for (int ct = 0; ct < 8; ++ct) {
      const int vc = chb - 256 + ct * 16 + l15;
      const float bb = kv_b[vc + 256];
      uint2 u;
      u.x = pk_bf16(kacc[ct][0] + bb, kacc[ct][1] + bb);
      u.y = pk_bf16(kacc[ct][2] + bb, kacc[ct][3] + bb);
      const int h = vc >> 5, d = vc & 31;
      *(uint2*)&vtbf[((size_t)(b * HEADS + h) * HD + d) * NKV + tl + qd * 4] = u;
    }
  }
}

// ---------------------------------------------------------------------------
// MFMA flash attention v7: 256 queries/block (4 query tiles, processed in
// pairs to bound VGPR), 64-key chunks double-buffered via global_load_lds,
// l via ones-MFMA, no-max softmax. One barrier per chunk. Grid (16, 8, 4).
// LDS units: buf0 [0,512), buf1 [512,1024); P at 1024 + w*544 + qt*136.
// ---------------------------------------------------------------------------
__global__ __launch_bounds__(256) void attn_mfma(
    const unsigned short* __restrict__ qbf,
    const unsigned short* __restrict__ kbf,
    const unsigned short* __restrict__ vtbf,
    unsigned short* __restrict__ abf) {
  __shared__ unsigned short sm[25856];   // 3232 units = 50.5 KB
  const int tid = threadIdx.x, w = tid >> 6, ln = tid & 63;
  const int l15 = ln & 15, qd = ln >> 4;
  const int h = blockIdx.y, b = blockIdx.z;
  const int bh = b * HEADS + h;
  const unsigned short* kbase = kbf + (size_t)bh * NKV * HD;
  const unsigned short* vtbase = vtbf + (size_t)bh * HD * NKV;
  const int q0 = blockIdx.x * 256 + w * 16 + l15;
  short8 qf[4];
#pragma unroll
  for (int qt = 0; qt < 4; ++qt)
    qf[qt] = *(const short8*)(qbf + ((size_t)bh * NN + q0 + qt * 64) * HD + qd * 8);
  const short8 ones = {16256, 16256, 16256, 16256, 16256, 16256, 16256, 16256};
  floatx4 a0[4], a1[4], al[4];
#pragma unroll
  for (int qt = 0; qt < 4; ++qt)
#pragma unroll
    for (int r = 0; r < 4; ++r) { a0[qt][r] = 0.f; a1[qt][r] = 0.f; al[qt][r] = 0.f; }
  const int pu = 1024 + w * 544;

  // prologue: stage chunk 0 into buf0
#pragma unroll
  for (int it = 0; it < 2; ++it) {
    const unsigned short* src;
    if (w < 2) {
      const int t = w * 2 + it;
      src = kbase + (size_t)(t * 16 + l15) * HD + qd * 8;
    } else {
      src = vtbase + (size_t)(it * 16 + l15) * NKV + (w - 2) * 32 + qd * 8;
    }
    gl_lds16(src, sm + (w * 128 + it * 64) * 8);
  }

  for (int cc = 0; cc < 16; ++cc) {
    __syncthreads();   // drains this chunk's staging; fences buffer reuse
    const int cb = (cc & 1) * 512;
    if (cc < 15) {     // stage next chunk into the other buffer
      const int sb = 512 - cb;
      const int t0n = (cc + 1) * 64;
#pragma unroll
      for (int it = 0; it < 2; ++it) {
        const unsigned short* src;
        if (w < 2) {
          const int t = w * 2 + it;
          src = kbase + (size_t)(t0n + t * 16 + l15) * HD + qd * 8;
        } else {
          src = vtbase + (size_t)(it * 16 + l15) * NKV + t0n + (w - 2) * 32 + qd * 8;
        }
        gl_lds16(src, sm + (sb + w * 128 + it * 64) * 8);
      }
    }
#pragma unroll
    for (int p = 0; p < 2; ++p) {
      const int qA = p * 2, qB = p * 2 + 1;
      const int pbA = pu + qA * 136, pbB = pu + qB * 136;
      // QK: 4 key tiles, both tiles of the pair off one kf read
      floatx4 sA[4], sB[4];
#pragma unroll
      for (int t = 0; t < 4; ++t) {
        short8 kf = *(const short8*)(sm + (cb + t * 64 + ln) * 8);
        floatx4 z; for (int r = 0; r < 4; ++r) z[r] = 0.f;
        sA[t] = __builtin_amdgcn_mfma_f32_16x16x32_bf16(kf, qf[qA], z, 0, 0, 0);
        sB[t] = __builtin_amdgcn_mfma_f32_16x16x32_bf16(kf, qf[qB], z, 0, 0, 0);
      }
#pragma unroll
      for (int t = 0; t < 4; ++t) {
        const int uoff = (t >> 1) * 68 + ((t & 1) * 2 + (qd >> 1)) * 16 + l15;
        uint2 pk;
        pk.x = pk_bf16(__builtin_amdgcn_exp2f(sA[t][0]), __builtin_amdgcn_exp2f(sA[t][1]));
        pk.y = pk_bf16(__builtin_amdgcn_exp2f(sA[t][2]), __builtin_amdgcn_exp2f(sA[t][3]));
        *(uint2*)(sm + (pbA + uoff) * 8 + (qd & 1) * 4) = pk;
        pk.x = pk_bf16(__builtin_amdgcn_exp2f(sB[t][0]), __builtin_amdgcn_exp2f(sB[t][1]));
        pk.y = pk_bf16(__builtin_amdgcn_exp2f(sB[t][2]), __builtin_amdgcn_exp2f(sB[t][3]));
        *(uint2*)(sm + (pbB + uoff) * 8 + (qd & 1) * 4) = pk;
      }
      // PV: V fragments shared across the pair; l via ones-MFMA
#pragma unroll
      for (int kg = 0; kg < 2; ++kg) {
        short8 v0 = *(const short8*)(sm + (cb + 256 + kg * 128 + ln) * 8);
        short8 v1 = *(const short8*)(sm + (cb + 256 + kg * 128 + 64 + ln) * 8);
        short8 pfA = *(const short8*)(sm + (pbA + kg * 68 + ln) * 8);
        short8 pfB = *(const short8*)(sm + (pbB + kg * 68 + ln) * 8);
        a0[qA] = __builtin_amdgcn_mfma_f32_16x16x32_bf16(v0, pfA, a0[qA], 0, 0, 0);
        a1[qA] = __builtin_amdgcn_mfma_f32_16x16x32_bf16(v1, pfA, a1[qA], 0, 0, 0);
        a0[qB] = __builtin_amdgcn_mfma_f32_16x16x32_bf16(v0, pfB, a0[qB], 0, 0, 0);
        a1[qB] = __builtin_amdgcn_mfma_f32_16x16x32_bf16(v1, pfB, a1[qB], 0, 0, 0);
        al[qA] = __builtin_amdgcn_mfma_f32_16x16x32_bf16(ones, pfA, al[qA], 0, 0, 0);
        al[qB] = __builtin_amdgcn_mfma_f32_16x16x32_bf16(ones, pfB, al[qB], 0, 0, 0);
      }
    }
  }
#pragma unroll
  for (int qt = 0; qt < 4; ++qt) {
    const float inv = 1.f / al[qt][0];
    unsigned short* ob = abf + ((size_t)b * NN + q0 + qt * 64) * CCH + h * HD;
    uint2 u0, u1;
    u0.x = pk_bf16(a0[qt][0] * inv, a0[qt][1] * inv);
    u0.y = pk_bf16(a0[qt][2] * inv, a0[qt][3] * inv);
    u1.x = pk_bf16(a1[qt][0] * inv, a1[qt][1] * inv);
    u1.y = pk_bf16(a1[qt][2] * inv, a1[qt][3] * inv);
    *(uint2*)(ob + qd * 4) = u0;
    *(uint2*)(ob + 16 + qd * 4) = u1;
  }
}

// ---------------------------------------------------------------------------
// Output projection: block = 16 tokens x 256 ch (4 waves), swizzled W.
// Grid 1024, fp32 out.
// ---------------------------------------------------------------------------
__global__ __launch_bounds__(256) void proj_gemm(const unsigned short* __restrict__ abf,
    const unsigned short* __restrict__ p_wbf, const float* __restrict__ p_b,
    float* __restrict__ out) {
  __shared__ unsigned short xs[8448];
  const int tid = threadIdx.x, w = tid >> 6, ln = tid & 63;
  const int l15 = ln & 15, qd = ln >> 4;
  const long tok0 = (long)blockIdx.x * 16;
#pragma unroll
  for (int j = 0; j < 2; ++j) {
    const int idx = j * 256 + tid;
    const int tok = idx >> 5, u = idx & 31;
    *(uint4*)(xs + XU16(tok, u)) =
        *(const uint4*)(abf + (tok0 + tok) * 256 + u * 8);
  }
  __syncthreads();
  floatx4 acc[4];
#pragma unroll
  for (int ct = 0; ct < 4; ++ct) for (int r = 0; r < 4; ++r) acc[ct][r] = 0.f;
  const unsigned short* wb = p_wbf + (size_t)(w * 4) * 4096 + ln * 8;
#pragma unroll
  for (int kc = 0; kc < 8; ++kc) {
    short8 xf = *(const short8*)(xs + XU16(l15, kc * 4 + qd));
#pragma unroll
    for (int ct = 0; ct < 4; ++ct) {
      short8 wf = *(const short8*)(wb + (ct * 8 + kc) * 512);
      acc[ct] = __builtin_amdgcn_mfma_f32_16x16x32_bf16(wf, xf, acc[ct], 0, 0, 0);
    }
  }
  const long tok = tok0 + l15;
  const int chb = w * 64;
#pragma unroll
  for (int ct = 0; ct < 4; ++ct) {
    const int ch = chb + ct * 16 + qd * 4;
    float4 bb = *(const float4*)&p_b[ch];
    float4 o;
    o.x = acc[ct][0] + bb.x; o.y = acc[ct][1] + bb.y;
    o.z = acc[ct][2] + bb.z; o.w = acc[ct][3] + bb.w;
    *(float4*)&out[(size_t)tok * 256 + ch] = o;
  }
}

// ---------------------------------------------------------------------------
extern "C" void kernel_launch(void* const* d_in, const int* in_sizes, int n_in,
                              void* d_out, int out_size, void* d_ws, size_t ws_size,
                              hipStream_t stream) {
  const float* x      = (const float*)d_in[0];
  const float* q_w    = (const float*)d_in[1];
  const float* q_b    = (const float*)d_in[2];
  const float* kv_w   = (const float*)d_in[3];
  const float* kv_b   = (const float*)d_in[4];
  const float* sr_w   = (const float*)d_in[5];
  const float* sr_b   = (const float*)d_in[6];
  const float* ln_g   = (const float*)d_in[7];
  const float* ln_b   = (const float*)d_in[8];
  const float* proj_w = (const float*)d_in[9];
  const float* proj_b = (const float*)d_in[10];
  float* out = (float*)d_out;

  char* base = (char*)d_ws;
  const size_t MB = 1048576;
  unsigned short* q_wbf    = (unsigned short*)(base);                 // 128 KB
  unsigned short* kv_wbf   = (unsigned short*)(base + 131072);        // 256 KB
  unsigned short* sr_wbf   = (unsigned short*)(base + 393216);        // 512 KB
  unsigned short* proj_wbf = (unsigned short*)(base + 917504);        // 128 KB
  unsigned short* q_bf     = (unsigned short*)(base + 1 * MB);        // 8 MB
  unsigned short* k_bf     = (unsigned short*)(base + 9 * MB);        // 2 MB
  unsigned short* vt_bf    = (unsigned short*)(base + 11 * MB);       // 2 MB
  unsigned short* attn_bf  = (unsigned short*)(base + 13 * MB);       // 8 MB

  cast_weights<<<256, 256, 0, stream>>>(q_w, kv_w, sr_w, proj_w,
                                        q_wbf, kv_wbf, sr_wbf, proj_wbf);
  qconv_gemm<<<1280, 256, 0, stream>>>(x, q_wbf, q_b, sr_wbf, sr_b, ln_g, ln_b,
                                       kv_wbf, kv_b, q_bf, k_bf, vt_bf);
  attn_mfma<<<dim3(16, HEADS, BB), 256, 0, stream>>>(q_bf, k_bf, vt_bf, attn_bf);
  proj_gemm<<<1024, 256, 0, stream>>>(attn_bf, proj_wbf, proj_b, out);
}

// Round 9
// 159.184 us; speedup vs baseline: 1.0182x; 1.0182x over previous
//
#include <hip/hip_runtime.h>
#include <hip/hip_bf16.h>
#include <math.h>

#define BB 4
#define NN 4096
#define CCH 256
#define HEADS 8
#define HD 32
#define NKV 1024
#define EPS_LN 1e-5f

typedef short short8 __attribute__((ext_vector_type(8)));
typedef float floatx4 __attribute__((ext_vector_type(4)));

// scale = HD^-0.5 folded with log2(e): softmax runs in exp2 domain
#define QSCALE (0.17677669529663687f * 1.4426950408889634f)

__device__ __forceinline__ unsigned pk_bf16(float a, float b) {
  __hip_bfloat162 h = __float22bfloat162_rn(make_float2(a, b));
  unsigned u; __builtin_memcpy(&u, &h, 4); return u;
}

__device__ __forceinline__ short8 cvt8(float4 a, float4 b) {
  union { short8 s; unsigned u[4]; } r;
  r.u[0] = pk_bf16(a.x, a.y); r.u[1] = pk_bf16(a.z, a.w);
  r.u[2] = pk_bf16(b.x, b.y); r.u[3] = pk_bf16(b.z, b.w);
  return r.s;
}

// ---------------------------------------------------------------------------
// Cast weights fp32 -> bf16, FRAGMENT-MAJOR swizzle:
// unit(row,col) = ((row>>4)*(Kd/32) + (col>>5))*64 + ((col>>3)&3)*16 + (row&15)
// -> a wave's wf load is one contiguous 1KB segment. QSCALE folded into q_w.
// ---------------------------------------------------------------------------
__global__ __launch_bounds__(256) void cast_weights(
    const float* __restrict__ q_w, const float* __restrict__ kv_w,
    const float* __restrict__ sr_w, const float* __restrict__ proj_w,
    unsigned short* __restrict__ q_wbf, unsigned short* __restrict__ kv_wbf,
    unsigned short* __restrict__ sr_wbf, unsigned short* __restrict__ proj_wbf) {
  const int e = (blockIdx.x * 256 + threadIdx.x) * 8;
  const float* src; unsigned short* dst; int off; int shift, kdu; float sc = 1.f;
  if (e < 65536)       { src = q_w;    dst = q_wbf;    off = e;          shift = 8;  kdu = 8;  sc = QSCALE; }
  else if (e < 196608) { src = kv_w;   dst = kv_wbf;   off = e - 65536;  shift = 8;  kdu = 8; }
  else if (e < 458752) { src = sr_w;   dst = sr_wbf;   off = e - 196608; shift = 10; kdu = 32; }
  else                 { src = proj_w; dst = proj_wbf; off = e - 458752; shift = 8;  kdu = 8; }
  const int row = off >> shift;
  const int col = off & ((1 << shift) - 1);
  const int unit = ((row >> 4) * kdu + (col >> 5)) * 64 + ((col >> 3) & 3) * 16 + (row & 15);
  float4 a = *(const float4*)&src[off];
  float4 b = *(const float4*)&src[off + 4];
  a.x *= sc; a.y *= sc; a.z *= sc; a.w *= sc;
  b.x *= sc; b.y *= sc; b.z *= sc; b.w *= sc;
  *(short8*)&dst[unit * 8] = cvt8(a, b);
}

// X-tile LDS layout (16 tokens x 32 16B-units, 33-unit skew)
#define XU16(t, u) (((t) * 33 + (u)) * 8)

// ---------------------------------------------------------------------------
// Fused Q-projection + (SR-conv + LN + KV-projection).
// Grid 1280 x 256 thr: bx < 1024 -> Q tile (16 tok x 256 ch);
// bx >= 1024 -> conv tile: 16 kv tok, conv full-K per wave, in-LDS LN, KV
// GEMM. V is emitted in the attention fragment-major global layout:
// unit = ((chunk*2 + kg)*2 + dhalf)*64 + kq*16 + dlow  (16B units per head).
// ---------------------------------------------------------------------------
__global__ __launch_bounds__(256) void qconv_gemm(const float* __restrict__ x,
    const unsigned short* __restrict__ q_wbf, const float* __restrict__ q_b,
    const unsigned short* __restrict__ sr_wbf, const float* __restrict__ sr_b,
    const float* __restrict__ ln_g, const float* __restrict__ ln_b,
    const unsigned short* __restrict__ kv_wbf, const float* __restrict__ kv_b,
    unsigned short* __restrict__ qbf,
    unsigned short* __restrict__ kbf, unsigned short* __restrict__ vtbf) {
  __shared__ unsigned short sm[20736];
  const int tid = threadIdx.x, w = tid >> 6, lnn = tid & 63;
  const int l15 = lnn & 15, qd = lnn >> 4;

  if (blockIdx.x < 1024) {
    // ---------------- Q projection tile ----------------
    const long tok0 = (long)blockIdx.x * 16;
    const float* Xg = x + tok0 * 256;
#pragma unroll
    for (int j = 0; j < 2; ++j) {
      const int idx = j * 256 + tid;
      const int tok = idx >> 5, u = idx & 31;
      float4 a = *(const float4*)(Xg + (size_t)tok * 256 + u * 8);
      float4 b = *(const float4*)(Xg + (size_t)tok * 256 + u * 8 + 4);
      *(short8*)(sm + XU16(tok, u)) = cvt8(a, b);
    }
    __syncthreads();
    floatx4 acc[4];
#pragma unroll
    for (int ct = 0; ct < 4; ++ct) for (int r = 0; r < 4; ++r) acc[ct][r] = 0.f;
    const unsigned short* wb = q_wbf + (size_t)(w * 4) * 4096 + lnn * 8;
#pragma unroll
    for (int kc = 0; kc < 8; ++kc) {
      short8 xf = *(const short8*)(sm + XU16(l15, kc * 4 + qd));
#pragma unroll
      for (int ct = 0; ct < 4; ++ct) {
        short8 wf = *(const short8*)(wb + (ct * 8 + kc) * 512);
        acc[ct] = __builtin_amdgcn_mfma_f32_16x16x32_bf16(wf, xf, acc[ct], 0, 0, 0);
      }
    }
    const int tok = (int)tok0 + l15;
    const int b = tok >> 12, trow = tok & 4095;
    const int chb = w * 64;
#pragma unroll
    for (int ct = 0; ct < 4; ++ct) {
      const int ch = chb + ct * 16 + qd * 4;
      float4 bb = *(const float4*)&q_b[ch];
      uint2 u;
      u.x = pk_bf16(acc[ct][0] + bb.x * QSCALE, acc[ct][1] + bb.y * QSCALE);
      u.y = pk_bf16(acc[ct][2] + bb.z * QSCALE, acc[ct][3] + bb.w * QSCALE);
      const int h = ch >> 5, d0 = ch & 31;
      *(uint2*)&qbf[((size_t)(b * HEADS + h) * NN + trow) * HD + d0] = u;
    }
    return;
  }

  // ---------------- conv + LN + KV tile ----------------
  unsigned short* xs = sm + 16512;
  const int gt0 = (blockIdx.x - 1024) * 16;
  const int b = gt0 >> 10, tl = gt0 & 1023;
#pragma unroll
  for (int j = 0; j < 8; ++j) {
    const int g = j * 256 + tid;
    const int tk = g >> 7, u = g & 127;
    const int c0 = u * 2;
    const int tt = tl + tk;
    const int ti = tt >> 5, tj = tt & 31;
    float4 va, vb;
    float* pa = (float*)&va; float* pb = (float*)&vb;
#pragma unroll
    for (int q = 0; q < 4; ++q) {
      const int row = (2 * ti + (q >> 1)) * 64 + 2 * tj + (q & 1);
      const float* s = &x[((size_t)b * NN + row) * CCH + c0];
      pa[q] = s[0]; pb[q] = s[1];
    }
    *(short8*)(sm + (tk * 129 + u) * 8) = cvt8(va, vb);
  }
  __syncthreads();
  floatx4 acc[4];
#pragma unroll
  for (int ct = 0; ct < 4; ++ct) for (int r = 0; r < 4; ++r) acc[ct][r] = 0.f;
  const unsigned short* wbc = sr_wbf + lnn * 8;
#pragma unroll
  for (int kc = 0; kc < 32; ++kc) {
    short8 xf = *(const short8*)(sm + (l15 * 129 + kc * 4 + qd) * 8);
#pragma unroll
    for (int ct = 0; ct < 4; ++ct) {
      short8 wf = *(const short8*)(wbc + ((w * 4 + ct) * 32 + kc) * 512);
      acc[ct] = __builtin_amdgcn_mfma_f32_16x16x32_bf16(wf, xf, acc[ct], 0, 0, 0);
    }
  }
  __syncthreads();
  float* ft = (float*)sm;
#pragma unroll
  for (int ct = 0; ct < 4; ++ct) {
    float4 o;
    o.x = acc[ct][0]; o.y = acc[ct][1]; o.z = acc[ct][2]; o.w = acc[ct][3];
    *(float4*)&ft[l15 * 260 + w * 64 + ct * 16 + qd * 4] = o;
  }
  __syncthreads();
  {
    const int tk = tid >> 4, l16 = tid & 15;
    float v[16];
    float4* vv = (float4*)v;
#pragma unroll
    for (int m = 0; m < 4; ++m) {
      float4 t = *(float4*)&ft[tk * 260 + l16 * 16 + m * 4];
      float4 sb = *(const float4*)&sr_b[l16 * 16 + m * 4];
      t.x += sb.x; t.y += sb.y; t.z += sb.z; t.w += sb.w;
      vv[m] = t;
    }
    float s1 = 0.f, s2 = 0.f;
#pragma unroll
    for (int i = 0; i < 16; ++i) { s1 += v[i]; s2 += v[i] * v[i]; }
#pragma unroll
    for (int off = 1; off < 16; off <<= 1) {
      s1 += __shfl_xor(s1, off);
      s2 += __shfl_xor(s2, off);
    }
    const float mu = s1 * (1.f / 256.f);
    const float rstd = rsqrtf(s2 * (1.f / 256.f) - mu * mu + EPS_LN);
#pragma unroll
    for (int m = 0; m < 2; ++m) {
      float4 ga = *(const float4*)&ln_g[l16 * 16 + m * 8];
      float4 gb = *(const float4*)&ln_g[l16 * 16 + m * 8 + 4];
      float4 ba = *(const float4*)&ln_b[l16 * 16 + m * 8];
      float4 bb = *(const float4*)&ln_b[l16 * 16 + m * 8 + 4];
      float4 oa, ob;
      oa.x = (vv[m * 2].x - mu) * rstd * ga.x + ba.x;
      oa.y = (vv[m * 2].y - mu) * rstd * ga.y + ba.y;
      oa.z = (vv[m * 2].z - mu) * rstd * ga.z + ba.z;
      oa.w = (vv[m * 2].w - mu) * rstd * ga.w + ba.w;
      ob.x = (vv[m * 2 + 1].x - mu) * rstd * gb.x + bb.x;
      ob.y = (vv[m * 2 + 1].y - mu) * rstd * gb.y + bb.y;
      ob.z = (vv[m * 2 + 1].z - mu) * rstd * gb.z + bb.z;
      ob.w = (vv[m * 2 + 1].w - mu) * rstd * gb.w + bb.w;
      *(short8*)(xs + XU16(tk, l16 * 2 + m)) = cvt8(oa, ob);
    }
  }
  __syncthreads();
  const bool isV = (w >= 2);
  const int chb = w * 128;
  floatx4 kacc[8];
#pragma unroll
  for (int ct = 0; ct < 8; ++ct) for (int r = 0; r < 4; ++r) kacc[ct][r] = 0.f;
  const unsigned short* wb = kv_wbf + (size_t)(chb >> 4) * 4096 + lnn * 8;
  if (!isV) {
#pragma unroll
    for (int kc = 0; kc < 8; ++kc) {
      short8 xf = *(const short8*)(xs + XU16(l15, kc * 4 + qd));
#pragma unroll
      for (int ct = 0; ct < 8; ++ct) {
        short8 wf = *(const short8*)(wb + (ct * 8 + kc) * 512);
        kacc[ct] = __builtin_amdgcn_mfma_f32_16x16x32_bf16(wf, xf, kacc[ct], 0, 0, 0);
      }
    }
    const int tok = tl + l15;
#pragma unroll
    for (int ct = 0; ct < 8; ++ct) {
      const int ch = chb + ct * 16 + qd * 4;
      float4 bb = *(const float4*)&kv_b[ch];
      uint2 u;
      u.x = pk_bf16(kacc[ct][0] + bb.x, kacc[ct][1] + bb.y);
      u.y = pk_bf16(kacc[ct][2] + bb.z, kacc[ct][3] + bb.w);
      const int h = ch >> 5, d0 = ch & 31;
      *(uint2*)&kbf[((size_t)(b * HEADS + h) * NKV + tok) * HD + d0] = u;
    }
  } else {
#pragma unroll
    for (int kc = 0; kc < 8; ++kc) {
      short8 xf = *(const short8*)(xs + XU16(l15, kc * 4 + qd));
#pragma unroll
      for (int ct = 0; ct < 8; ++ct) {
        short8 wf = *(const short8*)(wb + (ct * 8 + kc) * 512);
        kacc[ct] = __builtin_amdgcn_mfma_f32_16x16x32_bf16(xf, wf, kacc[ct], 0, 0, 0);
      }
    }
    // frag-major V store: tokens tl + qd*4 + r, lane l15 -> channel
    const int ccv = tl >> 6;
    const int base6 = (tl & 63) + qd * 4;
    const int kg = (base6 >> 5) & 1, kq = (base6 >> 3) & 3, j0 = base6 & 7;
#pragma unroll
    for (int ct = 0; ct < 8; ++ct) {
      const int vc = chb - 256 + ct * 16 + l15;
      const float bb = kv_b[vc + 256];
      uint2 u;
      u.x = pk_bf16(kacc[ct][0] + bb, kacc[ct][1] + bb);
      u.y = pk_bf16(kacc[ct][2] + bb, kacc[ct][3] + bb);
      const int hh = vc >> 5, d = vc & 31;
      const int half = d >> 4, dl = d & 15;
      const int unit = ((ccv * 2 + kg) * 2 + half) * 64 + kq * 16 + dl;
      *(uint2*)&vtbf[(size_t)(b * HEADS + hh) * 32768 + unit * 8 + j0] = u;
    }
  }
}

// ---------------------------------------------------------------------------
// MFMA flash attention v8: BARRIER-FREE. K and V fragments loaded straight
// from global (L2) into registers -- coalesced 1KB/wave (V pre-swizzled to
// fragment-major by qconv). Only P round-trips LDS, and P is wave-private
// (same-wave DS ordering via lgkmcnt -> zero __syncthreads). 64 q/wave
// (4 qt share each kf/v register set), reg-double-buffered chunks.
// Grid (16, 8, 4) x 256.
// ---------------------------------------------------------------------------
__global__ __launch_bounds__(256) void attn_mfma(
    const unsigned short* __restrict__ qbf,
    const unsigned short* __restrict__ kbf,
    const unsigned short* __restrict__ vtbf,
    unsigned short* __restrict__ abf) {
  __shared__ unsigned short sm[17408];   // 4 waves x 544 units (P only)
  const int tid = threadIdx.x, w = tid >> 6, ln = tid & 63;
  const int l15 = ln & 15, qd = ln >> 4;
  const int h = blockIdx.y, b = blockIdx.z;
  const int bh = b * HEADS + h;
  const unsigned short* kbase = kbf + (size_t)bh * NKV * HD;
  const unsigned short* vfb = vtbf + (size_t)bh * 32768;
  const int q0 = blockIdx.x * 256 + w * 64 + l15;   // + qt*16
  short8 qf[4];
#pragma unroll
  for (int qt = 0; qt < 4; ++qt)
    qf[qt] = *(const short8*)(qbf + ((size_t)bh * NN + q0 + qt * 16) * HD + qd * 8);
  const short8 ones = {16256, 16256, 16256, 16256, 16256, 16256, 16256, 16256};
  floatx4 a0[4], a1[4], al[4];
#pragma unroll
  for (int qt = 0; qt < 4; ++qt)
#pragma unroll
    for (int r = 0; r < 4; ++r) { a0[qt][r] = 0.f; a1[qt][r] = 0.f; al[qt][r] = 0.f; }
  const int pu = w * 544;   // wave-private P base (16B units)

  short8 kfA[4], vA[4], kfB[4], vB[4];
#define LOADKV(KF, VV, CC) do {                                               \
    const unsigned short* kp = kbase + ((size_t)(CC) * 64 + l15) * HD + qd * 8; \
    _Pragma("unroll")                                                          \
    for (int t = 0; t < 4; ++t) (KF)[t] = *(const short8*)(kp + t * 16 * HD);  \
    const unsigned short* vp = vfb + ((size_t)(CC) * 256 + ln) * 8;            \
    _Pragma("unroll")                                                          \
    for (int u = 0; u < 4; ++u) (VV)[u] = *(const short8*)(vp + u * 512);      \
  } while (0)

#define CHUNK(KF, VV) do {                                                     \
    _Pragma("unroll")                                                          \
    for (int qt = 0; qt < 4; ++qt) {                                           \
      const int pq = pu + qt * 136;                                            \
      floatx4 s[4];                                                            \
      _Pragma("unroll")                                                        \
      for (int t = 0; t < 4; ++t) {                                            \
        floatx4 z; for (int r = 0; r < 4; ++r) z[r] = 0.f;                     \
        s[t] = __builtin_amdgcn_mfma_f32_16x16x32_bf16((KF)[t], qf[qt], z, 0, 0, 0); \
      }                                                                        \
      _Pragma("unroll")                                                        \
      for (int t = 0; t < 4; ++t) {                                            \
        uint2 pk;                                                              \
        pk.x = pk_bf16(__builtin_amdgcn_exp2f(s[t][0]), __builtin_amdgcn_exp2f(s[t][1])); \
        pk.y = pk_bf16(__builtin_amdgcn_exp2f(s[t][2]), __builtin_amdgcn_exp2f(s[t][3])); \
        const int unit = pq + (t >> 1) * 68 + ((t & 1) * 2 + (qd >> 1)) * 16 + l15; \
        *(uint2*)(sm + unit * 8 + (qd & 1) * 4) = pk;                          \
      }                                                                        \
      _Pragma("unroll")                                                        \
      for (int kg = 0; kg < 2; ++kg) {                                         \
        short8 pf = *(const short8*)(sm + (pq + kg * 68 + ln) * 8);            \
        a0[qt] = __builtin_amdgcn_mfma_f32_16x16x32_bf16((VV)[kg * 2], pf, a0[qt], 0, 0, 0);     \
        a1[qt] = __builtin_amdgcn_mfma_f32_16x16x32_bf16((VV)[kg * 2 + 1], pf, a1[qt], 0, 0, 0); \
        al[qt] = __builtin_amdgcn_mfma_f32_16x16x32_bf16(ones, pf, al[qt], 0, 0, 0);             \
      }                                                                        \
    }                                                                          \
  } while (0)

  LOADKV(kfA, vA, 0);
  for (int cc = 0; cc < 16; cc += 2) {
    LOADKV(kfB, vB, cc + 1);
    CHUNK(kfA, vA);
    if (cc + 2 < 16) LOADKV(kfA, vA, cc + 2);
    CHUNK(kfB, vB);
  }
#undef LOADKV
#undef CHUNK

#pragma unroll
  for (int qt = 0; qt < 4; ++qt) {
    const float inv = 1.f / al[qt][0];
    unsigned short* ob = abf + ((size_t)b * NN + q0 + qt * 16) * CCH + h * HD;
    uint2 u0, u1;
    u0.x = pk_bf16(a0[qt][0] * inv, a0[qt][1] * inv);
    u0.y = pk_bf16(a0[qt][2] * inv, a0[qt][3] * inv);
    u1.x = pk_bf16(a1[qt][0] * inv, a1[qt][1] * inv);
    u1.y = pk_bf16(a1[qt][2] * inv, a1[qt][3] * inv);
    *(uint2*)(ob + qd * 4) = u0;
    *(uint2*)(ob + 16 + qd * 4) = u1;
  }
}

// ---------------------------------------------------------------------------
// Output projection: block = 16 tokens x 256 ch (4 waves), swizzled W.
// Grid 1024, fp32 out.
// ---------------------------------------------------------------------------
__global__ __launch_bounds__(256) void proj_gemm(const unsigned short* __restrict__ abf,
    const unsigned short* __restrict__ p_wbf, const float* __restrict__ p_b,
    float* __restrict__ out) {
  __shared__ unsigned short xs[8448];
  const int tid = threadIdx.x, w = tid >> 6, ln = tid & 63;
  const int l15 = ln & 15, qd = ln >> 4;
  const long tok0 = (long)blockIdx.x * 16;
#pragma unroll
  for (int j = 0; j < 2; ++j) {
    const int idx = j * 256 + tid;
    const int tok = idx >> 5, u = idx & 31;
    *(uint4*)(xs + XU16(tok, u)) =
        *(const uint4*)(abf + (tok0 + tok) * 256 + u * 8);
  }
  __syncthreads();
  floatx4 acc[4];
#pragma unroll
  for (int ct = 0; ct < 4; ++ct) for (int r = 0; r < 4; ++r) acc[ct][r] = 0.f;
  const unsigned short* wb = p_wbf + (size_t)(w * 4) * 4096 + ln * 8;
#pragma unroll
  for (int kc = 0; kc < 8; ++kc) {
    short8 xf = *(const short8*)(xs + XU16(l15, kc * 4 + qd));
#pragma unroll
    for (int ct = 0; ct < 4; ++ct) {
      short8 wf = *(const short8*)(wb + (ct * 8 + kc) * 512);
      acc[ct] = __builtin_amdgcn_mfma_f32_16x16x32_bf16(wf, xf, acc[ct], 0, 0, 0);
    }
  }
  const long tok = tok0 + l15;
  const int chb = w * 64;
#pragma unroll
  for (int ct = 0; ct < 4; ++ct) {
    const int ch = chb + ct * 16 + qd * 4;
    float4 bb = *(const float4*)&p_b[ch];
    float4 o;
    o.x = acc[ct][0] + bb.x; o.y = acc[ct][1] + bb.y;
    o.z = acc[ct][2] + bb.z; o.w = acc[ct][3] + bb.w;
    *(float4*)&out[(size_t)tok * 256 + ch] = o;
  }
}

// ---------------------------------------------------------------------------
extern "C" void kernel_launch(void* const* d_in, const int* in_sizes, int n_in,
                              void* d_out, int out_size, void* d_ws, size_t ws_size,
                              hipStream_t stream) {
  const float* x      = (const float*)d_in[0];
  const float* q_w    = (const float*)d_in[1];
  const float* q_b    = (const float*)d_in[2];
  const float* kv_w   = (const float*)d_in[3];
  const float* kv_b   = (const float*)d_in[4];
  const float* sr_w   = (const float*)d_in[5];
  const float* sr_b   = (const float*)d_in[6];
  const float* ln_g   = (const float*)d_in[7];
  const float* ln_b   = (const float*)d_in[8];
  const float* proj_w = (const float*)d_in[9];
  const float* proj_b = (const float*)d_in[10];
  float* out = (float*)d_out;

  char* base = (char*)d_ws;
  const size_t MB = 1048576;
  unsigned short* q_wbf    = (unsigned short*)(base);                 // 128 KB
  unsigned short* kv_wbf   = (unsigned short*)(base + 131072);        // 256 KB
  unsigned short* sr_wbf   = (unsigned short*)(base + 393216);        // 512 KB
  unsigned short* proj_wbf = (unsigned short*)(base + 917504);        // 128 KB
  unsigned short* q_bf     = (unsigned short*)(base + 1 * MB);        // 8 MB
  unsigned short* k_bf     = (unsigned short*)(base + 9 * MB);        // 2 MB
  unsigned short* vt_bf    = (unsigned short*)(base + 11 * MB);       // 2 MB
  unsigned short* attn_bf  = (unsigned short*)(base + 13 * MB);       // 8 MB

  cast_weights<<<256, 256, 0, stream>>>(q_w, kv_w, sr_w, proj_w,
                                        q_wbf, kv_wbf, sr_wbf, proj_wbf);
  qconv_gemm<<<1280, 256, 0, stream>>>(x, q_wbf, q_b, sr_wbf, sr_b, ln_g, ln_b,
                                       kv_wbf, kv_b, q_bf, k_bf, vt_bf);
  attn_mfma<<<dim3(16, HEADS, BB), 256, 0, stream>>>(q_bf, k_bf, vt_bf, attn_bf);
  proj_gemm<<<1024, 256, 0, stream>>>(attn_bf, proj_wbf, proj_b, out);
}

// Round 10
// 158.140 us; speedup vs baseline: 1.0249x; 1.0066x over previous
//
#include <hip/hip_runtime.h>
#include <hip/hip_bf16.h>
#include <math.h>

#define BB 4
#define NN 4096
#define CCH 256
#define HEADS 8
#define HD 32
#define NKV 1024
#define EPS_LN 1e-5f

typedef short short8 __attribute__((ext_vector_type(8)));
typedef float floatx4 __attribute__((ext_vector_type(4)));

// scale = HD^-0.5 folded with log2(e): softmax runs in exp2 domain
#define QSCALE (0.17677669529663687f * 1.4426950408889634f)

__device__ __forceinline__ unsigned pk_bf16(float a, float b) {
  __hip_bfloat162 h = __float22bfloat162_rn(make_float2(a, b));
  unsigned u; __builtin_memcpy(&u, &h, 4); return u;
}

__device__ __forceinline__ short8 cvt8(float4 a, float4 b) {
  union { short8 s; unsigned u[4]; } r;
  r.u[0] = pk_bf16(a.x, a.y); r.u[1] = pk_bf16(a.z, a.w);
  r.u[2] = pk_bf16(b.x, b.y); r.u[3] = pk_bf16(b.z, b.w);
  return r.s;
}

// ---------------------------------------------------------------------------
// Cast weights fp32 -> bf16, FRAGMENT-MAJOR swizzle:
// unit(row,col) = ((row>>4)*(Kd/32) + (col>>5))*64 + ((col>>3)&3)*16 + (row&15)
// -> a wave's wf load is one contiguous 1KB segment. QSCALE folded into q_w.
// sr_w additionally gets K permuted to QUADRANT-MAJOR: col' = q*256 + c
// (patch staging in qconv writes the same order -> coalesced, no gather).
// ---------------------------------------------------------------------------
__global__ __launch_bounds__(256) void cast_weights(
    const float* __restrict__ q_w, const float* __restrict__ kv_w,
    const float* __restrict__ sr_w, const float* __restrict__ proj_w,
    unsigned short* __restrict__ q_wbf, unsigned short* __restrict__ kv_wbf,
    unsigned short* __restrict__ sr_wbf, unsigned short* __restrict__ proj_wbf) {
  const int e = (blockIdx.x * 256 + threadIdx.x) * 8;
  if (e >= 196608 && e < 458752) {
    // sr_w: 8 consecutive src elems = (row, c0..c0+1, q0..3), c0 even
    const int off = e - 196608;
    const int row = off >> 10;
    const int wr = off & 1023;
    const int c0 = (wr >> 3) * 2;
    float4 a = *(const float4*)&sr_w[off];
    float4 b = *(const float4*)&sr_w[off + 4];
    const float v[8] = {a.x, a.y, a.z, a.w, b.x, b.y, b.z, b.w};
    const int base = (row >> 4) * 32;   // Kd/32 = 32
#pragma unroll
    for (int q = 0; q < 4; ++q) {
      const int unit = (base + q * 8 + (c0 >> 5)) * 64 + ((c0 >> 3) & 3) * 16 + (row & 15);
      *(unsigned*)&sr_wbf[unit * 8 + (c0 & 7)] = pk_bf16(v[q], v[4 + q]);
    }
    return;
  }
  const float* src; unsigned short* dst; int off; float sc = 1.f;
  if (e < 65536)       { src = q_w;    dst = q_wbf;    off = e;          sc = QSCALE; }
  else if (e < 196608) { src = kv_w;   dst = kv_wbf;   off = e - 65536; }
  else                 { src = proj_w; dst = proj_wbf; off = e - 458752; }
  const int row = off >> 8;
  const int col = off & 255;
  const int unit = ((row >> 4) * 8 + (col >> 5)) * 64 + ((col >> 3) & 3) * 16 + (row & 15);
  float4 a = *(const float4*)&src[off];
  float4 b = *(const float4*)&src[off + 4];
  a.x *= sc; a.y *= sc; a.z *= sc; a.w *= sc;
  b.x *= sc; b.y *= sc; b.z *= sc; b.w *= sc;
  *(short8*)&dst[unit * 8] = cvt8(a, b);
}

// X-tile LDS layout (16 tokens x 32 16B-units, 33-unit skew)
#define XU16(t, u) (((t) * 33 + (u)) * 8)

// ---------------------------------------------------------------------------
// Fused (SR-conv + LN + KV-projection) + Q-projection.
// Grid 1280 x 256 thr: bx < 256 -> conv tile (heavier -> dispatched FIRST);
// bx >= 256 -> Q tile (16 tok x 256 ch).
// Conv tile: 16 kv tok; patch staged COALESCED in quadrant-major order
// (f = q*256 + c, matching the sr_w K-permutation); conv full-K per wave;
// in-LDS LN; KV GEMM. V emitted in attention fragment-major layout:
// unit = ((chunk*2 + kg)*2 + dhalf)*64 + kq*16 + dlow  (16B units per head).
// ---------------------------------------------------------------------------
__global__ __launch_bounds__(256) void qconv_gemm(const float* __restrict__ x,
    const unsigned short* __restrict__ q_wbf, const float* __restrict__ q_b,
    const unsigned short* __restrict__ sr_wbf, const float* __restrict__ sr_b,
    const float* __restrict__ ln_g, const float* __restrict__ ln_b,
    const unsigned short* __restrict__ kv_wbf, const float* __restrict__ kv_b,
    unsigned short* __restrict__ qbf,
    unsigned short* __restrict__ kbf, unsigned short* __restrict__ vtbf) {
  __shared__ unsigned short sm[20736];
  const int tid = threadIdx.x, w = tid >> 6, lnn = tid & 63;
  const int l15 = lnn & 15, qd = lnn >> 4;

  if (blockIdx.x >= 256) {
    // ---------------- Q projection tile ----------------
    const long tok0 = (long)(blockIdx.x - 256) * 16;
    const float* Xg = x + tok0 * 256;
#pragma unroll
    for (int j = 0; j < 2; ++j) {
      const int idx = j * 256 + tid;
      const int tok = idx >> 5, u = idx & 31;
      float4 a = *(const float4*)(Xg + (size_t)tok * 256 + u * 8);
      float4 b = *(const float4*)(Xg + (size_t)tok * 256 + u * 8 + 4);
      *(short8*)(sm + XU16(tok, u)) = cvt8(a, b);
    }
    __syncthreads();
    floatx4 acc[4];
#pragma unroll
    for (int ct = 0; ct < 4; ++ct) for (int r = 0; r < 4; ++r) acc[ct][r] = 0.f;
    const unsigned short* wb = q_wbf + (size_t)(w * 4) * 4096 + lnn * 8;
#pragma unroll
    for (int kc = 0; kc < 8; ++kc) {
      short8 xf = *(const short8*)(sm + XU16(l15, kc * 4 + qd));
#pragma unroll
      for (int ct = 0; ct < 4; ++ct) {
        short8 wf = *(const short8*)(wb + (ct * 8 + kc) * 512);
        acc[ct] = __builtin_amdgcn_mfma_f32_16x16x32_bf16(wf, xf, acc[ct], 0, 0, 0);
      }
    }
    const int tok = (int)tok0 + l15;
    const int b = tok >> 12, trow = tok & 4095;
    const int chb = w * 64;
#pragma unroll
    for (int ct = 0; ct < 4; ++ct) {
      const int ch = chb + ct * 16 + qd * 4;
      float4 bb = *(const float4*)&q_b[ch];
      uint2 u;
      u.x = pk_bf16(acc[ct][0] + bb.x * QSCALE, acc[ct][1] + bb.y * QSCALE);
      u.y = pk_bf16(acc[ct][2] + bb.z * QSCALE, acc[ct][3] + bb.w * QSCALE);
      const int h = ch >> 5, d0 = ch & 31;
      *(uint2*)&qbf[((size_t)(b * HEADS + h) * NN + trow) * HD + d0] = u;
    }
    return;
  }

  // ---------------- conv + LN + KV tile ----------------
  unsigned short* xs = sm + 16512;
  const int gt0 = blockIdx.x * 16;
  const int b = gt0 >> 10, tl = gt0 & 1023;
  const int ti = (tl & 1023) >> 5;
  const int cbase = 2 * (tl & 31);
  // coalesced patch staging: 64 x-tokens (2 rows x 32 cols) x 256 ch fp32.
  // dst feature f = q*256 + c (quadrant-major), q = di*2 + dj.
#pragma unroll
  for (int it = 0; it < 8; ++it) {
    const int g = it * 256 + tid;     // 0..2047 16B-units
    const int xt = g >> 5, u = g & 31;
    const int di = xt >> 5, cj = xt & 31;
    const int row = (2 * ti + di) * 64 + cbase + cj;
    const float* s = &x[((size_t)b * NN + row) * CCH + u * 8];
    float4 a = *(const float4*)s;
    float4 b2 = *(const float4*)(s + 4);
    const int tk = cj >> 1, q = di * 2 + (cj & 1);
    *(short8*)(sm + (tk * 129 + q * 32 + u) * 8) = cvt8(a, b2);
  }
  __syncthreads();
  floatx4 acc[4];
#pragma unroll
  for (int ct = 0; ct < 4; ++ct) for (int r = 0; r < 4; ++r) acc[ct][r] = 0.f;
  const unsigned short* wbc = sr_wbf + lnn * 8;
#pragma unroll
  for (int kc = 0; kc < 32; ++kc) {
    short8 xf = *(const short8*)(sm + (l15 * 129 + kc * 4 + qd) * 8);
#pragma unroll
    for (int ct = 0; ct < 4; ++ct) {
      short8 wf = *(const short8*)(wbc + ((w * 4 + ct) * 32 + kc) * 512);
      acc[ct] = __builtin_amdgcn_mfma_f32_16x16x32_bf16(wf, xf, acc[ct], 0, 0, 0);
    }
  }
  __syncthreads();
  float* ft = (float*)sm;
#pragma unroll
  for (int ct = 0; ct < 4; ++ct) {
    float4 o;
    o.x = acc[ct][0]; o.y = acc[ct][1]; o.z = acc[ct][2]; o.w = acc[ct][3];
    *(float4*)&ft[l15 * 260 + w * 64 + ct * 16 + qd * 4] = o;
  }
  __syncthreads();
  {
    const int tk = tid >> 4, l16 = tid & 15;
    float v[16];
    float4* vv = (float4*)v;
#pragma unroll
    for (int m = 0; m < 4; ++m) {
      float4 t = *(float4*)&ft[tk * 260 + l16 * 16 + m * 4];
      float4 sb = *(const float4*)&sr_b[l16 * 16 + m * 4];
      t.x += sb.x; t.y += sb.y; t.z += sb.z; t.w += sb.w;
      vv[m] = t;
    }
    float s1 = 0.f, s2 = 0.f;
#pragma unroll
    for (int i = 0; i < 16; ++i) { s1 += v[i]; s2 += v[i] * v[i]; }
#pragma unroll
    for (int off = 1; off < 16; off <<= 1) {
      s1 += __shfl_xor(s1, off);
      s2 += __shfl_xor(s2, off);
    }
    const float mu = s1 * (1.f / 256.f);
    const float rstd = rsqrtf(s2 * (1.f / 256.f) - mu * mu + EPS_LN);
#pragma unroll
    for (int m = 0; m < 2; ++m) {
      float4 ga = *(const float4*)&ln_g[l16 * 16 + m * 8];
      float4 gb = *(const float4*)&ln_g[l16 * 16 + m * 8 + 4];
      float4 ba = *(const float4*)&ln_b[l16 * 16 + m * 8];
      float4 bb = *(const float4*)&ln_b[l16 * 16 + m * 8 + 4];
      float4 oa, ob;
      oa.x = (vv[m * 2].x - mu) * rstd * ga.x + ba.x;
      oa.y = (vv[m * 2].y - mu) * rstd * ga.y + ba.y;
      oa.z = (vv[m * 2].z - mu) * rstd * ga.z + ba.z;
      oa.w = (vv[m * 2].w - mu) * rstd * ga.w + ba.w;
      ob.x = (vv[m * 2 + 1].x - mu) * rstd * gb.x + bb.x;
      ob.y = (vv[m * 2 + 1].y - mu) * rstd * gb.y + bb.y;
      ob.z = (vv[m * 2 + 1].z - mu) * rstd * gb.z + bb.z;
      ob.w = (vv[m * 2 + 1].w - mu) * rstd * gb.w + bb.w;
      *(short8*)(xs + XU16(tk, l16 * 2 + m)) = cvt8(oa, ob);
    }
  }
  __syncthreads();
  const bool isV = (w >= 2);
  const int chb = w * 128;
  floatx4 kacc[8];
#pragma unroll
  for (int ct = 0; ct < 8; ++ct) for (int r = 0; r < 4; ++r) kacc[ct][r] = 0.f;
  const unsigned short* wb = kv_wbf + (size_t)(chb >> 4) * 4096 + lnn * 8;
  if (!isV) {
#pragma unroll
    for (int kc = 0; kc < 8; ++kc) {
      short8 xf = *(const short8*)(xs + XU16(l15, kc * 4 + qd));
#pragma unroll
      for (int ct = 0; ct < 8; ++ct) {
        short8 wf = *(const short8*)(wb + (ct * 8 + kc) * 512);
        kacc[ct] = __builtin_amdgcn_mfma_f32_16x16x32_bf16(wf, xf, kacc[ct], 0, 0, 0);
      }
    }
    const int tok = tl + l15;
#pragma unroll
    for (int ct = 0; ct < 8; ++ct) {
      const int ch = chb + ct * 16 + qd * 4;
      float4 bb = *(const float4*)&kv_b[ch];
      uint2 u;
      u.x = pk_bf16(kacc[ct][0] + bb.x, kacc[ct][1] + bb.y);
      u.y = pk_bf16(kacc[ct][2] + bb.z, kacc[ct][3] + bb.w);
      const int h = ch >> 5, d0 = ch & 31;
      *(uint2*)&kbf[((size_t)(b * HEADS + h) * NKV + tok) * HD + d0] = u;
    }
  } else {
#pragma unroll
    for (int kc = 0; kc < 8; ++kc) {
      short8 xf = *(const short8*)(xs + XU16(l15, kc * 4 + qd));
#pragma unroll
      for (int ct = 0; ct < 8; ++ct) {
        short8 wf = *(const short8*)(wb + (ct * 8 + kc) * 512);
        kacc[ct] = __builtin_amdgcn_mfma_f32_16x16x32_bf16(xf, wf, kacc[ct], 0, 0, 0);
      }
    }
    // frag-major V store: tokens tl + qd*4 + r, lane l15 -> channel
    const int ccv = tl >> 6;
    const int base6 = (tl & 63) + qd * 4;
    const int kg = (base6 >> 5) & 1, kq = (base6 >> 3) & 3, j0 = base6 & 7;
#pragma unroll
    for (int ct = 0; ct < 8; ++ct) {
      const int vc = chb - 256 + ct * 16 + l15;
      const float bb = kv_b[vc + 256];
      uint2 u;
      u.x = pk_bf16(kacc[ct][0] + bb, kacc[ct][1] + bb);
      u.y = pk_bf16(kacc[ct][2] + bb, kacc[ct][3] + bb);
      const int hh = vc >> 5, d = vc & 31;
      const int half = d >> 4, dl = d & 15;
      const int unit = ((ccv * 2 + kg) * 2 + half) * 64 + kq * 16 + dl;
      *(uint2*)&vtbf[(size_t)(b * HEADS + hh) * 32768 + unit * 8 + j0] = u;
    }
  }
}

// ---------------------------------------------------------------------------
// MFMA flash attention v8: BARRIER-FREE. K and V fragments loaded straight
// from global (L2) into registers -- coalesced 1KB/wave (V pre-swizzled to
// fragment-major by qconv). Only P round-trips LDS, and P is wave-private
// (same-wave DS ordering via lgkmcnt -> zero __syncthreads). 64 q/wave
// (4 qt share each kf/v register set), reg-double-buffered chunks.
// Grid (16, 8, 4) x 256.
// ---------------------------------------------------------------------------
__global__ __launch_bounds__(256) void attn_mfma(
    const unsigned short* __restrict__ qbf,
    const unsigned short* __restrict__ kbf,
    const unsigned short* __restrict__ vtbf,
    unsigned short* __restrict__ abf) {
  __shared__ unsigned short sm[17408];   // 4 waves x 544 units (P only)
  const int tid = threadIdx.x, w = tid >> 6, ln = tid & 63;
  const int l15 = ln & 15, qd = ln >> 4;
  const int h = blockIdx.y, b = blockIdx.z;
  const int bh = b * HEADS + h;
  const unsigned short* kbase = kbf + (size_t)bh * NKV * HD;
  const unsigned short* vfb = vtbf + (size_t)bh * 32768;
  const int q0 = blockIdx.x * 256 + w * 64 + l15;   // + qt*16
  short8 qf[4];
#pragma unroll
  for (int qt = 0; qt < 4; ++qt)
    qf[qt] = *(const short8*)(qbf + ((size_t)bh * NN + q0 + qt * 16) * HD + qd * 8);
  const short8 ones = {16256, 16256, 16256, 16256, 16256, 16256, 16256, 16256};
  floatx4 a0[4], a1[4], al[4];
#pragma unroll
  for (int qt = 0; qt < 4; ++qt)
#pragma unroll
    for (int r = 0; r < 4; ++r) { a0[qt][r] = 0.f; a1[qt][r] = 0.f; al[qt][r] = 0.f; }
  const int pu = w * 544;   // wave-private P base (16B units)

  short8 kfA[4], vA[4], kfB[4], vB[4];
#define LOADKV(KF, VV, CC) do {                                               \
    const unsigned short* kp = kbase + ((size_t)(CC) * 64 + l15) * HD + qd * 8; \
    _Pragma("unroll")                                                          \
    for (int t = 0; t < 4; ++t) (KF)[t] = *(const short8*)(kp + t * 16 * HD);  \
    const unsigned short* vp = vfb + ((size_t)(CC) * 256 + ln) * 8;            \
    _Pragma("unroll")                                                          \
    for (int u = 0; u < 4; ++u) (VV)[u] = *(const short8*)(vp + u * 512);      \
  } while (0)

#define CHUNK(KF, VV) do {                                                     \
    _Pragma("unroll")                                                          \
    for (int qt = 0; qt < 4; ++qt) {                                           \
      const int pq = pu + qt * 136;                                            \
      floatx4 s[4];                                                            \
      _Pragma("unroll")                                                        \
      for (int t = 0; t < 4; ++t) {                                            \
        floatx4 z; for (int r = 0; r < 4; ++r) z[r] = 0.f;                     \
        s[t] = __builtin_amdgcn_mfma_f32_16x16x32_bf16((KF)[t], qf[qt], z, 0, 0, 0); \
      }                                                                        \
      _Pragma("unroll")                                                        \
      for (int t = 0; t < 4; ++t) {                                            \
        uint2 pk;                                                              \
        pk.x = pk_bf16(__builtin_amdgcn_exp2f(s[t][0]), __builtin_amdgcn_exp2f(s[t][1])); \
        pk.y = pk_bf16(__builtin_amdgcn_exp2f(s[t][2]), __builtin_amdgcn_exp2f(s[t][3])); \
        const int unit = pq + (t >> 1) * 68 + ((t & 1) * 2 + (qd >> 1)) * 16 + l15; \
        *(uint2*)(sm + unit * 8 + (qd & 1) * 4) = pk;                          \
      }                                                                        \
      _Pragma("unroll")                                                        \
      for (int kg = 0; kg < 2; ++kg) {                                         \
        short8 pf = *(const short8*)(sm + (pq + kg * 68 + ln) * 8);            \
        a0[qt] = __builtin_amdgcn_mfma_f32_16x16x32_bf16((VV)[kg * 2], pf, a0[qt], 0, 0, 0);     \
        a1[qt] = __builtin_amdgcn_mfma_f32_16x16x32_bf16((VV)[kg * 2 + 1], pf, a1[qt], 0, 0, 0); \
        al[qt] = __builtin_amdgcn_mfma_f32_16x16x32_bf16(ones, pf, al[qt], 0, 0, 0);             \
      }                                                                        \
    }                                                                          \
  } while (0)

  LOADKV(kfA, vA, 0);
  for (int cc = 0; cc < 16; cc += 2) {
    LOADKV(kfB, vB, cc + 1);
    CHUNK(kfA, vA);
    if (cc + 2 < 16) LOADKV(kfA, vA, cc + 2);
    CHUNK(kfB, vB);
  }
#undef LOADKV
#undef CHUNK

#pragma unroll
  for (int qt = 0; qt < 4; ++qt) {
    const float inv = 1.f / al[qt][0];
    unsigned short* ob = abf + ((size_t)b * NN + q0 + qt * 16) * CCH + h * HD;
    uint2 u0, u1;
    u0.x = pk_bf16(a0[qt][0] * inv, a0[qt][1] * inv);
    u0.y = pk_bf16(a0[qt][2] * inv, a0[qt][3] * inv);
    u1.x = pk_bf16(a1[qt][0] * inv, a1[qt][1] * inv);
    u1.y = pk_bf16(a1[qt][2] * inv, a1[qt][3] * inv);
    *(uint2*)(ob + qd * 4) = u0;
    *(uint2*)(ob + 16 + qd * 4) = u1;
  }
}

// ---------------------------------------------------------------------------
// Output projection: block = 16 tokens x 256 ch (4 waves), swizzled W.
// Grid 1024, fp32 out.
// ---------------------------------------------------------------------------
__global__ __launch_bounds__(256) void proj_gemm(const unsigned short* __restrict__ abf,
    const unsigned short* __restrict__ p_wbf, const float* __restrict__ p_b,
    float* __restrict__ out) {
  __shared__ unsigned short xs[8448];
  const int tid = threadIdx.x, w = tid >> 6, ln = tid & 63;
  const int l15 = ln & 15, qd = ln >> 4;
  const long tok0 = (long)blockIdx.x * 16;
#pragma unroll
  for (int j = 0; j < 2; ++j) {
    const int idx = j * 256 + tid;
    const int tok = idx >> 5, u = idx & 31;
    *(uint4*)(xs + XU16(tok, u)) =
        *(const uint4*)(abf + (tok0 + tok) * 256 + u * 8);
  }
  __syncthreads();
  floatx4 acc[4];
#pragma unroll
  for (int ct = 0; ct < 4; ++ct) for (int r = 0; r < 4; ++r) acc[ct][r] = 0.f;
  const unsigned short* wb = p_wbf + (size_t)(w * 4) * 4096 + ln * 8;
#pragma unroll
  for (int kc = 0; kc < 8; ++kc) {
    short8 xf = *(const short8*)(xs + XU16(l15, kc * 4 + qd));
#pragma unroll
    for (int ct = 0; ct < 4; ++ct) {
      short8 wf = *(const short8*)(wb + (ct * 8 + kc) * 512);
      acc[ct] = __builtin_amdgcn_mfma_f32_16x16x32_bf16(wf, xf, acc[ct], 0, 0, 0);
    }
  }
  const long tok = tok0 + l15;
  const int chb = w * 64;
#pragma unroll
  for (int ct = 0; ct < 4; ++ct) {
    const int ch = chb + ct * 16 + qd * 4;
    float4 bb = *(const float4*)&p_b[ch];
    float4 o;
    o.x = acc[ct][0] + bb.x; o.y = acc[ct][1] + bb.y;
    o.z = acc[ct][2] + bb.z; o.w = acc[ct][3] + bb.w;
    *(float4*)&out[(size_t)tok * 256 + ch] = o;
  }
}

// ---------------------------------------------------------------------------
extern "C" void kernel_launch(void* const* d_in, const int* in_sizes, int n_in,
                              void* d_out, int out_size, void* d_ws, size_t ws_size,
                              hipStream_t stream) {
  const float* x      = (const float*)d_in[0];
  const float* q_w    = (const float*)d_in[1];
  const float* q_b    = (const float*)d_in[2];
  const float* kv_w   = (const float*)d_in[3];
  const float* kv_b   = (const float*)d_in[4];
  const float* sr_w   = (const float*)d_in[5];
  const float* sr_b   = (const float*)d_in[6];
  const float* ln_g   = (const float*)d_in[7];
  const float* ln_b   = (const float*)d_in[8];
  const float* proj_w = (const float*)d_in[9];
  const float* proj_b = (const float*)d_in[10];
  float* out = (float*)d_out;

  char* base = (char*)d_ws;
  const size_t MB = 1048576;
  unsigned short* q_wbf    = (unsigned short*)(base);                 // 128 KB
  unsigned short* kv_wbf   = (unsigned short*)(base + 131072);        // 256 KB
  unsigned short* sr_wbf   = (unsigned short*)(base + 393216);        // 512 KB
  unsigned short* proj_wbf = (unsigned short*)(base + 917504);        // 128 KB
  unsigned short* q_bf     = (unsigned short*)(base + 1 * MB);        // 8 MB
  unsigned short* k_bf     = (unsigned short*)(base + 9 * MB);        // 2 MB
  unsigned short* vt_bf    = (unsigned short*)(base + 11 * MB);       // 2 MB
  unsigned short* attn_bf  = (unsigned short*)(base + 13 * MB);       // 8 MB

  cast_weights<<<256, 256, 0, stream>>>(q_w, kv_w, sr_w, proj_w,
                                        q_wbf, kv_wbf, sr_wbf, proj_wbf);
  qconv_gemm<<<1280, 256, 0, stream>>>(x, q_wbf, q_b, sr_wbf, sr_b, ln_g, ln_b,
                                       kv_wbf, kv_b, q_bf, k_bf, vt_bf);
  attn_mfma<<<dim3(16, HEADS, BB), 256, 0, stream>>>(q_bf, k_bf, vt_bf, attn_bf);
  proj_gemm<<<1024, 256, 0, stream>>>(attn_bf, proj_wbf, proj_b, out);
}